// Round 8
// baseline (1255.504 us; speedup 1.0000x reference)
//
#include <hip/hip_runtime.h>
#include <cstddef>

// ---------------- problem constants ----------------
#define NB 16
#define NC 256
#define NH 32
#define NW 32
#define NK 81

// ---- LDS float offsets (total 16,064 floats = 64,256 B -> 2 blocks/CU) ----
// Half-row blocks: 16 px per block. Strides odd-in-quads (20=5q, 28=7q, 252=63q).
#define L_FG    0        // [256][20] filter-grad half-row
#define L_MRES  5120     // [81][20]  mapped residuals; C reuses as sg^2
#define L_FS    6740     // A/C: [32ch][9dy][28]=8064 ; B: [128ch][28]=3584 ; scores 4x[81][20]=6480
#define L_CB    14804    // [32][20] flt chunk buf (A); B reuses as anum partials [16][20]
#define L_SIGN  15444    // signed char[81*16] score signs (-1/0/+1), 324 floats
#define L_CL    15768    // cst copy [245]
#define L_ANUM  16013    // [16]
#define L_ALPHA 16029    // [16]
#define L_TOT   16064

#define SBUF(p) (L_FS + (p) * 1620)   // 4 score buffers [81][20]

__device__ __forceinline__ float4 ld4(const float* p) { return *reinterpret_cast<const float4*>(p); }
__device__ __forceinline__ void st4(float* p, float4 v) { *reinterpret_cast<float4*>(p) = v; }

// 1024 blocks = 16b x 32y x 2xh. Per XCD the 64 co-resident blocks = ONE batch (4MB L2).
__device__ __forceinline__ void map_by(int bi, int& b, int& y, int& x0) {
    int xcd = bi & 7, slot = bi >> 3;          // slot 0..127
    b = xcd * 2 + (slot >> 6);
    int rem = slot & 63;
    y = rem >> 1;
    x0 = (rem & 1) * 16;
}

// ---------------- constants / distance map (cst = ws[0..]) ----------------
__global__ void k_const(const float* lw, const float* mw, const float* sww,
                        const float* lsl, const float* fr, float* cst) {
    int tid = threadIdx.x;
    if (tid < 81) {
        int dy = tid / 9, dx = tid % 9;
        float dist = sqrtf((float)((dy - 4) * (dy - 4) + (dx - 4) * (dx - 4)));
        float lab = 0.f, mm = 0.f, ss = 0.f;
        for (int d = 0; d < 10; d++) {
            float diff = dist * 2.f - (float)d;
            float bv = (d < 9) ? fmaxf(0.f, 1.f - fabsf(diff))
                               : fminf(fmaxf(1.f + diff, 0.f), 1.f);
            lab += bv * lw[d];
            mm  += bv * mw[d];
            ss  += bv * sww[d];
        }
        cst[tid]       = lab;
        cst[81 + tid]  = 1.f / (1.f + expf(-mm));
        cst[162 + tid] = ss;
    } else if (tid == 81) {
        cst[243] = expf(lsl[0]);
    } else if (tid == 82) {
        cst[244] = fmaxf(fr[0] * fr[0], 1e-10f) * (1.f / 65536.f);
    } else if (tid >= 83 && tid < 89) {
        cst[245 + (tid - 83)] = 0.f;
    }
}

// ---------------- copy flt input -> d_out (working filter lives in out) ----------------
__global__ void k_copy(const float* __restrict__ src, float* __restrict__ dst) {
    int i = (blockIdx.x * 256 + threadIdx.x) * 4;
    st4(dst + i, ld4(src + i));
}

// ---- A/C correlation: acc[9dx][4px] over 8 chunks of 32 channels ----
// isA: operand = flt (global, staged to L_CB per chunk); else operand = L_FG.
__device__ __forceinline__ void corr_pass(float* S, const float* __restrict__ feat,
                                          const float* __restrict__ flt_g, bool isA,
                                          int b, int y, int x0, int tid,
                                          int g, int dyA, int octA,
                                          const float* const sp[3], float* const sfp[3],
                                          const bool sv[3], float acc[9][4]) {
    // zero fs (invalid slots + pads stay zero)
    const float4 z4 = make_float4(0.f, 0.f, 0.f, 0.f);
    for (int i = tid; i < 2016; i += 576) st4(S + L_FS + i * 4, z4);

#pragma unroll
    for (int dx = 0; dx < 9; dx++)
#pragma unroll
        for (int i = 0; i < 4; i++) acc[dx][i] = 0.f;

    const bool cbv = isA && (tid < 128);
    const float* cgp = flt_g + (((size_t)(b * NC + (tid >> 2))) * NH + y) * NW + x0 + (tid & 3) * 4;
    float* cfp = S + L_CB + (tid >> 2) * 20 + (tid & 3) * 4;

    float4 R[3], Rcb;
#pragma unroll
    for (int k = 0; k < 3; k++) if (sv[k]) R[k] = ld4(sp[k]);
    if (cbv) Rcb = ld4(cgp);
    __syncthreads();

#pragma unroll 1
    for (int chunk = 0; chunk < 8; chunk++) {
#pragma unroll
        for (int k = 0; k < 3; k++) if (sv[k]) st4(sfp[k], R[k]);
        if (cbv) st4(cfp, Rcb);
        __syncthreads();
        if (chunk < 7) {
            int off = (chunk + 1) * 32768;   // 32 ch * 1024 floats
#pragma unroll
            for (int k = 0; k < 3; k++) if (sv[k]) R[k] = ld4(sp[k] + off);
            if (cbv) Rcb = ld4(cgp + off);
        }
#pragma unroll
        for (int j = 0; j < 2; j++) {
            const int cl = g * 2 + j;
            const float* opp = isA ? (S + L_CB + cl * 20 + octA * 4)
                                   : (S + L_FG + (chunk * 32 + cl) * 20 + octA * 4);
            float4 o = ld4(opp);
            const float* wb = S + L_FS + cl * 252 + dyA * 28 + octA * 4;
            float4 w0 = ld4(wb), w1 = ld4(wb + 4), w2 = ld4(wb + 8);
            float w[12] = {w0.x, w0.y, w0.z, w0.w, w1.x, w1.y, w1.z, w1.w,
                           w2.x, w2.y, w2.z, w2.w};
            float ov[4] = {o.x, o.y, o.z, o.w};
#pragma unroll
            for (int dx = 0; dx < 9; dx++)
#pragma unroll
                for (int i = 0; i < 4; i++)
                    acc[dx][i] = fmaf(ov[i], w[dx + i], acc[dx][i]);
        }
        __syncthreads();
    }
    // 16 groups -> 4 score buffers, 4 phases
#pragma unroll 1
    for (int p = 0; p < 4; p++) {
        if ((g & 3) == p) {
            float* B = S + SBUF(g >> 2);
#pragma unroll
            for (int dx = 0; dx < 9; dx++) {
                int idx = (dyA * 9 + dx) * 20 + octA * 4;
                if (p == 0) {
                    st4(B + idx, make_float4(acc[dx][0], acc[dx][1], acc[dx][2], acc[dx][3]));
                } else {
                    float4 t = ld4(B + idx);
                    t.x += acc[dx][0]; t.y += acc[dx][1]; t.z += acc[dx][2]; t.w += acc[dx][3];
                    st4(B + idx, t);
                }
            }
        }
        __syncthreads();
    }
}

// ---------------- mega kernel: one block = (b, y, x-half), 3 iterations ----------------
__global__ __launch_bounds__(576, 4) void mega(const float* __restrict__ feat,
                                               float* __restrict__ flt_g,   // = out
                                               float* __restrict__ cst_g) {
    __shared__ float S[L_TOT];
    int b, y, x0; map_by(blockIdx.x, b, y, x0);
    const int tid = threadIdx.x;

    // A/C compute mapping: 16 groups x (9 dy x 4 oct(4px))
    const int g = tid / 36, s36 = tid - g * 36;
    const int dyA = s36 >> 2, octA = s36 & 3;
    // B mapping
    const bool actB = tid < 512;
    const int c_l = tid >> 2, octB = tid & 3;

    // A/C staging precompute: 1728 items = 32c x 9dy x 6q
    const float* sp[3]; float* sfp[3]; bool sv[3];
#pragma unroll
    for (int k = 0; k < 3; k++) {
        int i = tid + 576 * k;
        int c = i / 54, r = i - c * 54;
        int dy = r / 6, q = r - dy * 6;
        int qg = (x0 >> 2) - 1 + q;
        int ry = y + dy - 4;
        sv[k] = (qg >= 0 && qg < 8 && ry >= 0 && ry < 32);
        int ryc = sv[k] ? ry : 0, qgc = sv[k] ? qg : 0;
        sp[k] = feat + ((size_t)(b * NC + c)) * 1024 + ryc * 32 + qgc * 4;
        sfp[k] = S + L_FS + c * 252 + dy * 28 + q * 4;
    }
    // B staging precompute: 768 items = 128c x 6q  (row offset added per phase)
    const float* bp[2]; float* bfp[2]; bool bv[2]; int bqv[2];
#pragma unroll
    for (int k = 0; k < 2; k++) {
        int i = tid + 576 * k;
        int c = i / 6, q = i - c * 6;
        int qg = (x0 >> 2) - 1 + q;
        bool inb = (k == 0) || (tid < 192);
        bv[k] = inb && (qg >= 0 && qg < 8);
        int qgc = bv[k] ? qg : 0;
        bp[k] = feat + ((size_t)(b * NC + (inb ? c : 0))) * 1024 + qgc * 4;
        bfp[k] = S + L_FS + (inb ? c : 0) * 28 + q * 4;
        bqv[k] = 0;
    }
    (void)bqv;

    for (int i = tid; i < 245; i += 576) S[L_CL + i] = cst_g[i];
    __syncthreads();
    const float step = S[L_CL + 243];
    const float rw   = S[L_CL + 244];
    signed char* sgn_arr = (signed char*)(S + L_SIGN);

#pragma unroll 1
    for (int it = 0; it < 3; it++) {
        // ================= pass A =================
        float acc[9][4];
        corr_pass(S, feat, flt_g, true, b, y, x0, tid, g, dyA, octA, sp, sfp, sv, acc);

        float srcl = 0.f;
        if (tid < 324) {
            int k = tid >> 2, o = tid & 3;
            int idx = k * 20 + o * 4;
            float lab = S[L_CL + k], m = S[L_CL + 81 + k], sw = S[L_CL + 162 + k];
            float am = 0.5f * (1.f - m), ap = 0.5f * (1.f + m);
            float4 a0 = ld4(S + SBUF(0) + idx), a1 = ld4(S + SBUF(1) + idx);
            float4 a2 = ld4(S + SBUF(2) + idx), a3 = ld4(S + SBUF(3) + idx);
            float sv4[4] = {a0.x + a1.x + a2.x + a3.x, a0.y + a1.y + a2.y + a3.y,
                            a0.z + a1.z + a2.z + a3.z, a0.w + a1.w + a2.w + a3.w};
            float tr[4];
#pragma unroll
            for (int xi = 0; xi < 4; xi++) {
                float s = sv4[xi];
                float act = am * fabsf(s) + ap * s;
                float sg = (s > 0.f ? 1.f : 0.f) - (s < 0.f ? 1.f : 0.f);
                float msk = am * sg + ap;
                float lres = sw * (act - lab);
                srcl = fmaf(lres, lres, srcl);
                tr[xi] = msk * sw * lres;
                sgn_arr[k * 16 + o * 4 + xi] = (signed char)(int)sg;
            }
            st4(S + L_MRES + idx, make_float4(tr[0], tr[1], tr[2], tr[3]));
        }
#pragma unroll
        for (int off = 32; off > 0; off >>= 1) srcl += __shfl_down(srcl, off, 64);
        if ((tid & 63) == 0) atomicAdd(cst_g + 245 + it, srcl);
        __syncthreads();

        // ================= pass B =================
        {
            const float4 z4 = make_float4(0.f, 0.f, 0.f, 0.f);
            // zero possibly-invalid halo quads of fs [128][28]
            if (tid < 256) st4(S + L_FS + (tid >> 1) * 28 + (tid & 1) * 20, z4);

            float accB[2][4];
#pragma unroll
            for (int cg = 0; cg < 2; cg++)
#pragma unroll
                for (int i = 0; i < 4; i++) accB[cg][i] = 0.f;

            int p0 = 0;
            while (p0 < 18) { int ry = y + (p0 >> 1) - 4; if (ry >= 0 && ry < 32) break; p0++; }
            float4 RB[2];
            {
                int cg = p0 & 1, ry = y + (p0 >> 1) - 4;
#pragma unroll
                for (int k = 0; k < 2; k++)
                    if (bv[k]) RB[k] = ld4(bp[k] + cg * 131072 + ry * 32);
            }
            __syncthreads();

            float rr[9][4];
#pragma unroll 1
            for (int p = p0; p < 18; p++) {
                int dy = p >> 1, cg = p & 1, ry = y + dy - 4;
                if (ry < 0 || ry >= 32) continue;       // block-uniform
#pragma unroll
                for (int k = 0; k < 2; k++) if (bv[k]) st4(bfp[k], RB[k]);
                __syncthreads();
                int pn = p + 1;
                while (pn < 18) { int ryn = y + (pn >> 1) - 4; if (ryn >= 0 && ryn < 32) break; pn++; }
                if (pn < 18) {
                    int cgn = pn & 1, ryn = y + (pn >> 1) - 4;
#pragma unroll
                    for (int k = 0; k < 2; k++)
                        if (bv[k]) RB[k] = ld4(bp[k] + cgn * 131072 + ryn * 32);
                }
                if (actB) {
                    if (cg == 0) {
#pragma unroll
                        for (int dx = 0; dx < 9; dx++) {
                            float4 t = ld4(S + L_MRES + (dy * 9 + dx) * 20 + octB * 4);
                            rr[dx][0] = t.x; rr[dx][1] = t.y; rr[dx][2] = t.z; rr[dx][3] = t.w;
                        }
                    }
                    const float* wb = S + L_FS + c_l * 28 + octB * 4;
                    float4 w0 = ld4(wb), w1 = ld4(wb + 4), w2 = ld4(wb + 8);
                    float w[12] = {w0.x, w0.y, w0.z, w0.w, w1.x, w1.y, w1.z, w1.w,
                                   w2.x, w2.y, w2.z, w2.w};
#pragma unroll
                    for (int dx = 0; dx < 9; dx++)
#pragma unroll
                        for (int i = 0; i < 4; i++)
                            accB[cg][i] = fmaf(rr[dx][i], w[dx + i], accB[cg][i]);
                }
                __syncthreads();
            }
            // corr parts -> L_FG
            if (actB) {
#pragma unroll
                for (int cg = 0; cg < 2; cg++)
                    st4(S + L_FG + (cg * 128 + c_l) * 20 + octB * 4,
                        make_float4(accB[cg][0], accB[cg][1], accB[cg][2], accB[cg][3]));
            }
            __syncthreads();
            // fg += rw*flt (coalesced global reads); reg loss
            float regl = 0.f;
            for (int i = tid; i < 1024; i += 576) {
                int c = i >> 2, q = i & 3;
                float4 fl = ld4(flt_g + (((size_t)(b * NC + c)) * NH + y) * NW + x0 + q * 4);
                float* fp = S + L_FG + c * 20 + q * 4;
                float4 fc = ld4(fp);
                fc.x += rw * fl.x; fc.y += rw * fl.y; fc.z += rw * fl.z; fc.w += rw * fl.w;
                regl += fl.x * fl.x + fl.y * fl.y + fl.z * fl.z + fl.w * fl.w;
                st4(fp, fc);
            }
#pragma unroll
            for (int off = 32; off > 0; off >>= 1) regl += __shfl_down(regl, off, 64);
            if ((tid & 63) == 0) atomicAdd(cst_g + 248 + it, regl);
            __syncthreads();
            // alpha_num = sum_c fg^2 per x: partials [16][20] in L_CB
            if (tid < 256) {
                int c16 = tid >> 4, x = tid & 15;
                float s = 0.f;
                for (int cc = 0; cc < 16; cc++) {
                    float v = S[L_FG + (c16 * 16 + cc) * 20 + x];
                    s = fmaf(v, v, s);
                }
                S[L_CB + c16 * 20 + x] = s;
            }
            __syncthreads();
            if (tid < 16) {
                float s = 0.f;
#pragma unroll
                for (int k = 0; k < 16; k++) s += S[L_CB + k * 20 + tid];
                S[L_ANUM + tid] = s;
            }
            __syncthreads();
        }

        // ================= pass C =================
        float accC[9][4];
        corr_pass(S, feat, flt_g, false, b, y, x0, tid, g, dyA, octA, sp, sfp, sv, accC);

        if (tid < 324) {
            int k = tid >> 2, o = tid & 3;
            int idx = k * 20 + o * 4;
            float m = S[L_CL + 81 + k], sw = S[L_CL + 162 + k];
            float am = 0.5f * (1.f - m), ap = 0.5f * (1.f + m);
            float4 a0 = ld4(S + SBUF(0) + idx), a1 = ld4(S + SBUF(1) + idx);
            float4 a2 = ld4(S + SBUF(2) + idx), a3 = ld4(S + SBUF(3) + idx);
            float sv4[4] = {a0.x + a1.x + a2.x + a3.x, a0.y + a1.y + a2.y + a3.y,
                            a0.z + a1.z + a2.z + a3.z, a0.w + a1.w + a2.w + a3.w};
            float sq[4];
#pragma unroll
            for (int xi = 0; xi < 4; xi++) {
                float sg0 = (float)sgn_arr[k * 16 + o * 4 + xi];
                float msk = am * sg0 + ap;
                float sgv = sw * msk * sv4[xi];
                sq[xi] = sgv * sgv;
            }
            st4(S + L_MRES + idx, make_float4(sq[0], sq[1], sq[2], sq[3]));
        }
        __syncthreads();
        if (tid < 16) {
            float den = 0.f;
            for (int k = 0; k < 81; k++) den += S[L_MRES + k * 20 + tid];
            float num = S[L_ANUM + tid];
            float dd = fmaxf(den + rw * num, 1e-8f);
            S[L_ALPHA + tid] = step * num / dd;
        }
        __syncthreads();
        // update: flt(global) -= alpha * fg
        for (int i = tid; i < 1024; i += 576) {
            int c = i >> 2, q = i & 3;
            size_t go = (((size_t)(b * NC + c)) * NH + y) * NW + x0 + q * 4;
            float4 fl = ld4(flt_g + go);
            float4 fg = ld4(S + L_FG + c * 20 + q * 4);
            fl.x -= S[L_ALPHA + q * 4 + 0] * fg.x;
            fl.y -= S[L_ALPHA + q * 4 + 1] * fg.y;
            fl.z -= S[L_ALPHA + q * 4 + 2] * fg.z;
            fl.w -= S[L_ALPHA + q * 4 + 3] * fg.w;
            st4(flt_g + go, fl);
        }
        __syncthreads();
    }
}

// ---------------- tail: write tr, tr_src, tr_reg ----------------
__global__ void k_tail(const float* cst, float* out) {
    int i = threadIdx.x;
    if (i < 3) {
        float rw = cst[244];
        float src = 0.5f * cst[245 + i] / 16.f;
        float reg = 0.5f * rw * cst[248 + i] / 16.f;
        out[4194304 + i] = src + reg;
        out[4194307 + i] = src;
        out[4194310 + i] = reg;
    }
}

extern "C" void kernel_launch(void* const* d_in, const int* in_sizes, int n_in,
                              void* d_out, int out_size, void* d_ws, size_t ws_size,
                              hipStream_t stream) {
    (void)in_sizes; (void)n_in; (void)out_size; (void)ws_size;
    const float* flt_in = (const float*)d_in[0];
    const float* feat   = (const float*)d_in[1];
    const float* lw     = (const float*)d_in[2];
    const float* mw     = (const float*)d_in[3];
    const float* sww    = (const float*)d_in[4];
    const float* lsl    = (const float*)d_in[5];
    const float* fr     = (const float*)d_in[6];
    float* out = (float*)d_out;
    float* cst = (float*)d_ws;

    k_const<<<1, 128, 0, stream>>>(lw, mw, sww, lsl, fr, cst);
    k_copy<<<4096, 256, 0, stream>>>(flt_in, out);   // working filter lives in out
    mega<<<1024, 576, 0, stream>>>(feat, out, cst);
    k_tail<<<1, 64, 0, stream>>>(cst, out);
}

// Round 10
// 805.317 us; speedup vs baseline: 1.5590x; 1.5590x over previous
//
#include <hip/hip_runtime.h>
#include <cstddef>

// ---------------- problem constants ----------------
#define NB 16
#define NC 256
#define NH 32
#define NW 32
#define NK 81

// ---- LDS float offsets (total 18,821 fl = 75,284 B -> 2 blocks/CU) ----
#define L_MRES  0        // [81][36] mres / anum partials [64][36] / sg^2 scratch
#define L_SSC   2916     // [81][36] persistent raw scores (linearity trick)
#define L_FS    5832     // A/C stage [16][9][44]=6336 ; B stage [128][44]=5632 ; C-reduce 2x[81][36]
#define L_FGB   12168    // bf16 fg: ushort[256][40] = 5120 fl
#define L_CB    17288    // [16][36] A-operand chunk buf (it0 only)
#define L_SIGN  17864    // signed char[81*32] = 648 fl
#define L_CL    18512    // cst copy [245]
#define L_ANUM  18757    // [32]
#define L_ALPHA 18789    // [32]
#define L_TOT   18821

__device__ __forceinline__ float4 ld4(const float* p) { return *reinterpret_cast<const float4*>(p); }
__device__ __forceinline__ void st4(float* p, float4 v) { *reinterpret_cast<float4*>(p) = v; }
__device__ __forceinline__ float bl(unsigned int u) { union { unsigned int i; float f; } c; c.i = u; return c.f; }
__device__ __forceinline__ unsigned short f2b(float x) {
    unsigned int b = __float_as_uint(x);
    return (unsigned short)((b + 0x7fffu + ((b >> 16) & 1u)) >> 16);   // RNE
}

// ---------------- constants / distance map (cst = ws[0..]) ----------------
__global__ void k_const(const float* lw, const float* mw, const float* sww,
                        const float* lsl, const float* fr, float* cst) {
    int tid = threadIdx.x;
    if (tid < 81) {
        int dy = tid / 9, dx = tid % 9;
        float dist = sqrtf((float)((dy - 4) * (dy - 4) + (dx - 4) * (dx - 4)));
        float lab = 0.f, mm = 0.f, ss = 0.f;
        for (int d = 0; d < 10; d++) {
            float diff = dist * 2.f - (float)d;
            float bv = (d < 9) ? fmaxf(0.f, 1.f - fabsf(diff))
                               : fminf(fmaxf(1.f + diff, 0.f), 1.f);
            lab += bv * lw[d];
            mm  += bv * mw[d];
            ss  += bv * sww[d];
        }
        cst[tid]       = lab;
        cst[81 + tid]  = 1.f / (1.f + expf(-mm));
        cst[162 + tid] = ss;
    } else if (tid == 81) {
        cst[243] = expf(lsl[0]);
    } else if (tid == 82) {
        cst[244] = fmaxf(fr[0] * fr[0], 1e-10f) * (1.f / 65536.f);
    } else if (tid >= 83 && tid < 89) {
        cst[245 + (tid - 83)] = 0.f;
    }
}

// ---------------- feat fp32 -> bf16 (RNE) ----------------
__global__ void k_bf16(const float* __restrict__ src, unsigned short* __restrict__ dst) {
    int i = (blockIdx.x * 256 + threadIdx.x) * 4;
    float4 v = ld4(src + i);
    unsigned int u0 = (unsigned int)f2b(v.x) | ((unsigned int)f2b(v.y) << 16);
    unsigned int u1 = (unsigned int)f2b(v.z) | ((unsigned int)f2b(v.w) << 16);
    *reinterpret_cast<uint2*>(dst + i) = make_uint2(u0, u1);
}

// ---- A/C correlation pass: 16 chunks x 16 ch; result in 2 reduce bufs at L_FS/+2916 ----
__device__ __forceinline__ void corr_pass(float* S, const unsigned short* sp, bool sval,
                                          float* sfp, int g, int dyA, int octA, int tid,
                                          bool isA, bool own, int c_own, int q_own,
                                          const float4 F[4]) {
    const float4 z4 = make_float4(0.f, 0.f, 0.f, 0.f);
#pragma unroll
    for (int k = 0; k < 3; k++) { int i = tid + 576 * k; if (i < 1584) st4(S + L_FS + i * 4, z4); }
    __syncthreads();

    float acc[9][4];
#pragma unroll
    for (int dx = 0; dx < 9; dx++) { acc[dx][0] = acc[dx][1] = acc[dx][2] = acc[dx][3] = 0.f; }

#pragma unroll 1
    for (int ck = 0; ck < 16; ck++) {
        if (sval) {
            uint4 u = *reinterpret_cast<const uint4*>(sp + ck * 16384);
            st4(sfp,     make_float4(bl(u.x << 16), bl(u.x & 0xffff0000u),
                                     bl(u.y << 16), bl(u.y & 0xffff0000u)));
            st4(sfp + 4, make_float4(bl(u.z << 16), bl(u.z & 0xffff0000u),
                                     bl(u.w << 16), bl(u.w & 0xffff0000u)));
        }
        if (isA && own) {
#pragma unroll
            for (int j = 0; j < 4; j++) {
                int c = c_own + 64 * j;
                if ((c >> 4) == ck) st4(S + L_CB + (c & 15) * 36 + q_own * 4, F[j]);
            }
        }
        __syncthreads();
#pragma unroll
        for (int j = 0; j < 2; j++) {
            int cl = g * 2 + j;
            float4 o;
            if (isA) {
                o = ld4(S + L_CB + cl * 36 + octA * 4);
            } else {
                uint2 ub = *reinterpret_cast<const uint2*>(
                    (const unsigned short*)(S + L_FGB) + (ck * 16 + cl) * 40 + octA * 4);
                o = make_float4(bl(ub.x << 16), bl(ub.x & 0xffff0000u),
                                bl(ub.y << 16), bl(ub.y & 0xffff0000u));
            }
            const float* wb = S + L_FS + cl * 396 + dyA * 44 + octA * 4;
            float4 w0 = ld4(wb), w1 = ld4(wb + 4), w2 = ld4(wb + 8);
            float w[12] = {w0.x, w0.y, w0.z, w0.w, w1.x, w1.y, w1.z, w1.w,
                           w2.x, w2.y, w2.z, w2.w};
            float ov[4] = {o.x, o.y, o.z, o.w};
#pragma unroll
            for (int dx = 0; dx < 9; dx++)
#pragma unroll
                for (int i2 = 0; i2 < 4; i2++)
                    acc[dx][i2] = fmaf(ov[i2], w[dx + i2], acc[dx][i2]);
        }
        __syncthreads();
    }
    // 8 groups -> 2 buffers, 4 phases
#pragma unroll 1
    for (int p = 0; p < 4; p++) {
        if ((g & 3) == p) {
            float* B = S + L_FS + (g >> 2) * 2916;
#pragma unroll
            for (int dx = 0; dx < 9; dx++) {
                int idx = (dyA * 9 + dx) * 36 + octA * 4;
                if (p == 0) {
                    st4(B + idx, make_float4(acc[dx][0], acc[dx][1], acc[dx][2], acc[dx][3]));
                } else {
                    float4 t = ld4(B + idx);
                    t.x += acc[dx][0]; t.y += acc[dx][1]; t.z += acc[dx][2]; t.w += acc[dx][3];
                    st4(B + idx, t);
                }
            }
        }
        __syncthreads();
    }
}

// ---------------- mega: one block = (b,y) row; flt in registers; 3 iterations ----------------
__global__ __launch_bounds__(576, 5) void mega(const float* __restrict__ flt_in,
                                               const unsigned short* __restrict__ featb,
                                               float* __restrict__ out,
                                               float* __restrict__ cst_g) {
    __shared__ float S[L_TOT];
    const int tid = threadIdx.x;
    const int xcd = blockIdx.x & 7, slot = blockIdx.x >> 3;
    const int b = xcd * 2 + (slot >> 5), y = slot & 31;

    // A/C compute mapping: 8 groups x (9 dy x 8 oct(4px))
    const int g = tid / 72, s72 = tid - g * 72;
    const int dyA = s72 >> 3, octA = s72 & 7;
    // A/C staging: exactly one item per thread (16c x 9dy x 4 groups-of-8)
    const int sc = tid / 36, sr = tid - sc * 36;
    const int sdy = sr >> 2, sgq = sr & 3;
    const int sry = y + sdy - 4;
    const bool sval = (sry >= 0 && sry < 32);
    const unsigned short* sp = featb + ((size_t)(b * NC + sc)) * 1024 + (sval ? sry : 0) * 32 + sgq * 8;
    float* sfp = S + L_FS + sc * 396 + sdy * 44 + 4 + sgq * 8;
    // owner mapping (flt registers / pass B): 512 threads = 64c x 8q, 4 ch each
    const bool own = tid < 512;
    const int c_own = tid >> 3, q_own = tid & 7;

    float4 F[4];
    if (own) {
#pragma unroll
        for (int j = 0; j < 4; j++)
            F[j] = ld4(flt_in + (((size_t)(b * NC + c_own + 64 * j)) * NH + y) * NW + q_own * 4);
    }
    for (int i = tid; i < 245; i += 576) S[L_CL + i] = cst_g[i];
    __syncthreads();
    const float step = S[L_CL + 243], rw = S[L_CL + 244];
    signed char* sgn = (signed char*)(S + L_SIGN);
    const float4 z4 = make_float4(0.f, 0.f, 0.f, 0.f);

#pragma unroll 1
    for (int it = 0; it < 3; it++) {
        // ----- scores: real corr at it0; linear update otherwise -----
        if (it == 0) {
            corr_pass(S, sp, sval, sfp, g, dyA, octA, tid, true, own, c_own, q_own, F);
            for (int item = tid; item < 648; item += 576) {
                int k = item >> 3, q = item & 7, idx = k * 36 + q * 4;
                float4 a0 = ld4(S + L_FS + idx), a1 = ld4(S + L_FS + 2916 + idx);
                st4(S + L_SSC + idx, make_float4(a0.x + a1.x, a0.y + a1.y, a0.z + a1.z, a0.w + a1.w));
            }
            __syncthreads();
        }
        // ----- A-tail: mres, signs, src loss from Ssc -----
        float srcl = 0.f;
        for (int item = tid; item < 648; item += 576) {
            int k = item >> 3, q = item & 7, idx = k * 36 + q * 4;
            float lab = S[L_CL + k], m = S[L_CL + 81 + k], sw = S[L_CL + 162 + k];
            float am = 0.5f * (1.f - m), ap = 0.5f * (1.f + m);
            float4 sc4 = ld4(S + L_SSC + idx);
            float sv[4] = {sc4.x, sc4.y, sc4.z, sc4.w};
            float tr[4];
#pragma unroll
            for (int xi = 0; xi < 4; xi++) {
                float s = sv[xi];
                float act = am * fabsf(s) + ap * s;
                float sg0 = (s > 0.f ? 1.f : 0.f) - (s < 0.f ? 1.f : 0.f);
                float msk = am * sg0 + ap;
                float lres = sw * (act - lab);
                srcl = fmaf(lres, lres, srcl);
                tr[xi] = msk * sw * lres;
                sgn[k * 32 + q * 4 + xi] = (signed char)(int)sg0;
            }
            st4(S + L_MRES + idx, make_float4(tr[0], tr[1], tr[2], tr[3]));
        }
#pragma unroll
        for (int off = 32; off > 0; off >>= 1) srcl += __shfl_down(srcl, off, 64);
        if ((tid & 63) == 0) atomicAdd(cst_g + 245 + it, srcl);
        __syncthreads();

        // ----- pass B: fg = corr_T(mres) + rw*flt ; anum; reg loss -----
        {
            // zero halos of B stage rows [128][44]: offsets 0..3 and 36..39 (window reads reach 39)
            if (tid < 256) st4(S + L_FS + (tid >> 1) * 44 + (tid & 1) * 36, z4);
            float accB[4][4];
#pragma unroll
            for (int j = 0; j < 4; j++) { accB[j][0] = accB[j][1] = accB[j][2] = accB[j][3] = 0.f; }
            __syncthreads();
#pragma unroll 1
            for (int dy = 0; dy < 9; dy++) {
                int ry = y + dy - 4;
                if (ry < 0 || ry >= 32) continue;          // block-uniform
                float rr[9][4]; bool rrok = false;
#pragma unroll 1
                for (int h = 0; h < 2; h++) {
                    if (own) {                              // stage 128 ch (bf16->fp32)
                        int c_loc = tid >> 2, gq = tid & 3;
                        uint4 u = *reinterpret_cast<const uint4*>(
                            featb + ((size_t)(b * NC + h * 128 + c_loc)) * 1024 + ry * 32 + gq * 8);
                        float* d = S + L_FS + c_loc * 44 + 4 + gq * 8;
                        st4(d,     make_float4(bl(u.x << 16), bl(u.x & 0xffff0000u),
                                               bl(u.y << 16), bl(u.y & 0xffff0000u)));
                        st4(d + 4, make_float4(bl(u.z << 16), bl(u.z & 0xffff0000u),
                                               bl(u.w << 16), bl(u.w & 0xffff0000u)));
                    }
                    __syncthreads();
                    if (own) {
                        if (!rrok) {
#pragma unroll
                            for (int dx = 0; dx < 9; dx++) {
                                float4 t = ld4(S + L_MRES + (dy * 9 + dx) * 36 + q_own * 4);
                                rr[dx][0] = t.x; rr[dx][1] = t.y; rr[dx][2] = t.z; rr[dx][3] = t.w;
                            }
                            rrok = true;
                        }
#pragma unroll
                        for (int j = 0; j < 2; j++) {
                            int jg = h * 2 + j;
                            const float* wb = S + L_FS + (c_own + 64 * j) * 44 + q_own * 4;
                            float4 w0 = ld4(wb), w1 = ld4(wb + 4), w2 = ld4(wb + 8);
                            float w[12] = {w0.x, w0.y, w0.z, w0.w, w1.x, w1.y, w1.z, w1.w,
                                           w2.x, w2.y, w2.z, w2.w};
#pragma unroll
                            for (int dx = 0; dx < 9; dx++)
#pragma unroll
                                for (int i2 = 0; i2 < 4; i2++)
                                    accB[jg][i2] = fmaf(rr[dx][i2], w[dx + i2], accB[jg][i2]);
                        }
                    }
                    __syncthreads();
                }
            }
            float regl = 0.f;
            if (own) {
                float an[4] = {0.f, 0.f, 0.f, 0.f};
#pragma unroll
                for (int j = 0; j < 4; j++) {
                    float fv[4] = {F[j].x, F[j].y, F[j].z, F[j].w};
                    float gg[4];
#pragma unroll
                    for (int i2 = 0; i2 < 4; i2++) {
                        gg[i2] = accB[j][i2] + rw * fv[i2];
                        regl = fmaf(fv[i2], fv[i2], regl);
                        an[i2] = fmaf(gg[i2], gg[i2], an[i2]);
                    }
                    unsigned int u0 = (unsigned int)f2b(gg[0]) | ((unsigned int)f2b(gg[1]) << 16);
                    unsigned int u1 = (unsigned int)f2b(gg[2]) | ((unsigned int)f2b(gg[3]) << 16);
                    *reinterpret_cast<uint2*>((unsigned short*)(S + L_FGB)
                        + (c_own + 64 * j) * 40 + q_own * 4) = make_uint2(u0, u1);
                }
                st4(S + L_MRES + c_own * 36 + q_own * 4, make_float4(an[0], an[1], an[2], an[3]));
            }
#pragma unroll
            for (int off = 32; off > 0; off >>= 1) regl += __shfl_down(regl, off, 64);
            if ((tid & 63) == 0) atomicAdd(cst_g + 248 + it, regl);
            __syncthreads();
            if (tid < 32) {
                float s = 0.f;
                for (int r = 0; r < 64; r++) s += S[L_MRES + r * 36 + tid];
                S[L_ANUM + tid] = s;
            }
            __syncthreads();
        }

        // ----- pass C: raw Csc = corr(fg) -----
        corr_pass(S, sp, sval, sfp, g, dyA, octA, tid, false, own, c_own, q_own, F);

        // sg^2 -> mres (raw Csc preserved in the 2 buffers)
        for (int item = tid; item < 648; item += 576) {
            int k = item >> 3, q = item & 7, idx = k * 36 + q * 4;
            float m = S[L_CL + 81 + k], sw = S[L_CL + 162 + k];
            float am = 0.5f * (1.f - m), ap = 0.5f * (1.f + m);
            float4 a0 = ld4(S + L_FS + idx), a1 = ld4(S + L_FS + 2916 + idx);
            float cs[4] = {a0.x + a1.x, a0.y + a1.y, a0.z + a1.z, a0.w + a1.w};
            float sq[4];
#pragma unroll
            for (int xi = 0; xi < 4; xi++) {
                float sg0 = (float)sgn[k * 32 + q * 4 + xi];
                float msk = am * sg0 + ap;
                float v = sw * msk * cs[xi];
                sq[xi] = v * v;
            }
            st4(S + L_MRES + idx, make_float4(sq[0], sq[1], sq[2], sq[3]));
        }
        __syncthreads();
        if (tid < 32) {
            float den = 0.f;
            for (int k = 0; k < 81; k++) den += S[L_MRES + k * 36 + tid];
            float num = S[L_ANUM + tid];
            S[L_ALPHA + tid] = step * num / fmaxf(den + rw * num, 1e-8f);
        }
        __syncthreads();
        // Ssc -= alpha * Csc  (linearity: scores of updated filter)
        if (it < 2) {
            for (int item = tid; item < 648; item += 576) {
                int k = item >> 3, q = item & 7, idx = k * 36 + q * 4;
                float4 a0 = ld4(S + L_FS + idx), a1 = ld4(S + L_FS + 2916 + idx);
                float4 ss = ld4(S + L_SSC + idx);
                ss.x -= S[L_ALPHA + q * 4 + 0] * (a0.x + a1.x);
                ss.y -= S[L_ALPHA + q * 4 + 1] * (a0.y + a1.y);
                ss.z -= S[L_ALPHA + q * 4 + 2] * (a0.z + a1.z);
                ss.w -= S[L_ALPHA + q * 4 + 3] * (a0.w + a1.w);
                st4(S + L_SSC + idx, ss);
            }
        }
        // flt registers update
        if (own) {
            float al[4];
#pragma unroll
            for (int i2 = 0; i2 < 4; i2++) al[i2] = S[L_ALPHA + q_own * 4 + i2];
#pragma unroll
            for (int j = 0; j < 4; j++) {
                uint2 ub = *reinterpret_cast<const uint2*>(
                    (const unsigned short*)(S + L_FGB) + (c_own + 64 * j) * 40 + q_own * 4);
                F[j].x -= al[0] * bl(ub.x << 16);
                F[j].y -= al[1] * bl(ub.x & 0xffff0000u);
                F[j].z -= al[2] * bl(ub.y << 16);
                F[j].w -= al[3] * bl(ub.y & 0xffff0000u);
            }
        }
        __syncthreads();
    }

    // final: write flt registers to out
    if (own) {
#pragma unroll
        for (int j = 0; j < 4; j++)
            st4(out + (((size_t)(b * NC + c_own + 64 * j)) * NH + y) * NW + q_own * 4, F[j]);
    }
}

// ---------------- tail: write tr, tr_src, tr_reg ----------------
__global__ void k_tail(const float* cst, float* out) {
    int i = threadIdx.x;
    if (i < 3) {
        float rw = cst[244];
        float src = 0.5f * cst[245 + i] / 16.f;
        float reg = 0.5f * rw * cst[248 + i] / 16.f;
        out[4194304 + i] = src + reg;
        out[4194307 + i] = src;
        out[4194310 + i] = reg;
    }
}

extern "C" void kernel_launch(void* const* d_in, const int* in_sizes, int n_in,
                              void* d_out, int out_size, void* d_ws, size_t ws_size,
                              hipStream_t stream) {
    (void)in_sizes; (void)n_in; (void)out_size; (void)ws_size;
    const float* flt_in = (const float*)d_in[0];
    const float* feat   = (const float*)d_in[1];
    const float* lw     = (const float*)d_in[2];
    const float* mw     = (const float*)d_in[3];
    const float* sww    = (const float*)d_in[4];
    const float* lsl    = (const float*)d_in[5];
    const float* fr     = (const float*)d_in[6];
    float* out = (float*)d_out;
    float* cst = (float*)d_ws;
    unsigned short* featb = (unsigned short*)((float*)d_ws + 1024);

    k_const<<<1, 128, 0, stream>>>(lw, mw, sww, lsl, fr, cst);
    k_bf16<<<4096, 256, 0, stream>>>(feat, featb);
    mega<<<512, 576, 0, stream>>>(flt_in, featb, out, cst);
    k_tail<<<1, 64, 0, stream>>>(cst, out);
}